// Round 1
// baseline (699.386 us; speedup 1.0000x reference)
//
#include <hip/hip_runtime.h>
#include <stdint.h>

#define Bsz  256
#define Tlen 1024
#define Vocab 128
#define Hdim 128

__device__ __forceinline__ float tanh_fast(float x) {
    // tanh(x) = 1 - 2/(exp(2x)+1); exact limits at +-inf, abs err ~1e-7
    float e = __expf(2.0f * x);
    return 1.0f - 2.0f / (e + 1.0f);
}

// Fused prep: (a) decode one-hot rows -> symbol ids, one wave per (b,t);
//             (b) tail blocks transpose W_ih (H x V-1) -> wt (V-1 x H).
__global__ __launch_bounds__(256) void prep_kernel(
    const float* __restrict__ x, const float* __restrict__ W_ih,
    int* __restrict__ syms, float* __restrict__ wt)
{
    const int NDEC = (Bsz * Tlen) / 4;  // 65536 decode blocks, 4 waves each
    if (blockIdx.x < NDEC) {
        int pos  = (blockIdx.x << 2) + (threadIdx.x >> 6);
        int lane = threadIdx.x & 63;
        const float* row = x + (size_t)pos * Vocab;
        float v0 = row[lane];
        float v1 = row[lane + 64];
        unsigned long long m0 = __ballot(v0 > 0.5f);
        unsigned long long m1 = __ballot(v1 > 0.5f);
        int sym = m0 ? (int)__builtin_ctzll(m0) : 64 + (int)__builtin_ctzll(m1);
        if (lane == 0) syms[pos] = sym;
    } else {
        int idx = (blockIdx.x - NDEC) * 256 + threadIdx.x;
        if (idx < Hdim * (Vocab - 1)) {
            int h = idx / (Vocab - 1);
            int f = idx - h * (Vocab - 1);
            wt[f * Hdim + h] = W_ih[idx];   // wt[f][h] = W_ih[h][f]
        }
    }
}

// One block per sequence. 256 threads: lane pair (2k,2k+1) owns h-element
// i = wave*32 + k, each lane does 64 of the 128 MACs with W_hh row chunk in
// VGPRs; shfl_xor(1) combines; single barrier per step via double-buffered h.
__global__ __launch_bounds__(256) void rnn_kernel(
    const int* __restrict__ syms_g, const float* __restrict__ wt,
    const float* __restrict__ W_hh,
    const float* __restrict__ b_ih, const float* __restrict__ b_hh,
    const float* __restrict__ W_out, const float* __restrict__ b_out,
    float* __restrict__ out)
{
    __shared__ int   syms[Tlen];
    __shared__ float hbuf[2][Hdim];
    __shared__ int   len_sh;

    const int tid  = threadIdx.x;
    const int b    = blockIdx.x;
    const int wave = tid >> 6;
    const int l    = tid & 63;
    const int i    = (wave << 5) + (l >> 1);  // owned h element
    const int half = l & 1;                   // K-split half

    if (tid == 0) len_sh = Tlen;
    __syncthreads();

    // stage symbols into LDS + find first pad (length)
    int local_min = Tlen;
    for (int k = tid; k < Tlen; k += 256) {
        int s = syms_g[b * Tlen + k];
        syms[k] = s;
        if (s == 0 && k < local_min) local_min = k;
    }
    if (local_min < Tlen) atomicMin(&len_sh, local_min);

    if (tid < Hdim) hbuf[0][tid] = 0.0f;  // h0 = 0

    // W_hh row chunk -> registers (64 floats / lane)
    float4 w[16];
    const float4* wrow = (const float4*)(W_hh + i * Hdim + half * 64);
    #pragma unroll
    for (int k = 0; k < 16; k++) w[k] = wrow[k];

    const float bias = b_ih[i] + b_hh[i];

    __syncthreads();
    const int len = len_sh;

    // software-prefetched pre for step 0
    float pre_v = 0.0f;
    if (len > 0) pre_v = wt[(syms[0] - 1) * Hdim + i];

    for (int t = 0; t < len; t++) {
        // prefetch next step's W_ih column element (hidden behind FMAs)
        float pre_n = 0.0f;
        if (t + 1 < len) pre_n = wt[(syms[t + 1] - 1) * Hdim + i];

        const float4* hsrc = (const float4*)(hbuf[t & 1] + half * 64);
        float4 a = {0.0f, 0.0f, 0.0f, 0.0f};
        #pragma unroll
        for (int k = 0; k < 16; k++) {
            float4 hv = hsrc[k];
            a.x = fmaf(w[k].x, hv.x, a.x);
            a.y = fmaf(w[k].y, hv.y, a.y);
            a.z = fmaf(w[k].z, hv.z, a.z);
            a.w = fmaf(w[k].w, hv.w, a.w);
        }
        float sum = (a.x + a.y) + (a.z + a.w);
        sum += __shfl_xor(sum, 1, 64);           // combine K-halves
        float hn = tanh_fast(sum + pre_v + bias);
        if (half == 0) hbuf[(t + 1) & 1][i] = hn;
        pre_v = pre_n;
        __syncthreads();
    }

    // epilogue: hidden state + softmax head
    const float* hf = hbuf[len & 1];
    if (tid < Hdim) out[2 * Bsz + b * Hdim + tid] = hf[tid];
    if (wave == 0) {
        float p0 = W_out[l]       * hf[l] + W_out[64 + l]  * hf[64 + l];
        float p1 = W_out[128 + l] * hf[l] + W_out[192 + l] * hf[64 + l];
        #pragma unroll
        for (int off = 32; off > 0; off >>= 1) {
            p0 += __shfl_down(p0, off, 64);
            p1 += __shfl_down(p1, off, 64);
        }
        if (l == 0) {
            float l0 = p0 + b_out[0], l1 = p1 + b_out[1];
            float m  = fmaxf(l0, l1);
            float e0 = __expf(l0 - m), e1 = __expf(l1 - m);
            float d  = e0 + e1;
            out[b * 2 + 0] = e0 / d;
            out[b * 2 + 1] = e1 / d;
        }
    }
}

extern "C" void kernel_launch(void* const* d_in, const int* in_sizes, int n_in,
                              void* d_out, int out_size, void* d_ws, size_t ws_size,
                              hipStream_t stream) {
    const float* x     = (const float*)d_in[0];
    const float* W_ih  = (const float*)d_in[1];
    const float* W_hh  = (const float*)d_in[2];
    const float* b_ih  = (const float*)d_in[3];
    const float* b_hh  = (const float*)d_in[4];
    const float* W_out = (const float*)d_in[5];
    const float* b_out = (const float*)d_in[6];
    float* out = (float*)d_out;

    int*   syms = (int*)d_ws;                         // B*T ints = 1 MiB
    float* wt   = (float*)((char*)d_ws + (size_t)Bsz * Tlen * sizeof(int)); // 127*128 floats

    const int NDEC = (Bsz * Tlen) / 4;                // 65536
    const int NTRN = (Hdim * (Vocab - 1) + 255) / 256; // 64
    prep_kernel<<<NDEC + NTRN, 256, 0, stream>>>(x, W_ih, syms, wt);
    rnn_kernel<<<Bsz, 256, 0, stream>>>(syms, wt, W_hh, b_ih, b_hh, W_out, b_out, out);
}

// Round 2
// 673.886 us; speedup vs baseline: 1.0378x; 1.0378x over previous
//
#include <hip/hip_runtime.h>
#include <stdint.h>

#define Bsz   256
#define Tlen  1024
#define Vocab 128
#define Hdim  128
#define NTHR  512
#define CH    36   // padded LDS chunk stride in floats (32 data + 4 pad)

__device__ __forceinline__ float tanh_fast(float x) {
    // tanh(x) = 1 - 2/(exp(2x)+1); exact limits at +-inf, abs err ~1e-7
    float e = __expf(2.0f * x);
    return 1.0f - 2.0f / (e + 1.0f);
}

// Tiny prep: transpose W_ih (H x V-1) -> wt (V-1 x H) so the per-step
// "pre" gather is one contiguous 64B region per wave.
__global__ __launch_bounds__(256) void transpose_kernel(
    const float* __restrict__ W_ih, float* __restrict__ wt)
{
    int idx = blockIdx.x * 256 + threadIdx.x;
    if (idx < Hdim * (Vocab - 1)) {
        int h = idx / (Vocab - 1);
        int f = idx - h * (Vocab - 1);
        wt[f * Hdim + h] = W_ih[idx];   // wt[f][h] = W_ih[h][f]
    }
}

// One block (512 thr, 8 waves) per sequence. Lane quad (4 lanes) owns one
// h-output element i = wave*16 + (l>>2); each lane does 32 of the 128 MACs
// with its W_hh quarter-row pinned in VGPRs. h lives in LDS in 4 chunks of
// 32 floats at stride 36 (quarter bases -> banks 0/4/8/12: ds_read_b128
// conflict-free). One barrier per step via double buffering.
__global__ __launch_bounds__(NTHR) void rnn_kernel(
    const float* __restrict__ x, const float* __restrict__ wt,
    const float* __restrict__ W_hh,
    const float* __restrict__ b_ih, const float* __restrict__ b_hh,
    const float* __restrict__ W_out, const float* __restrict__ b_out,
    float* __restrict__ out)
{
    __shared__ int   syms[Tlen];
    __shared__ float hbuf[2][4 * CH];
    __shared__ int   len_sh;

    const int tid  = threadIdx.x;
    const int b    = blockIdx.x;
    const int wave = tid >> 6;
    const int l    = tid & 63;
    const int i    = (wave << 4) + (l >> 2);  // owned h element, 0..127
    const int q    = l & 3;                   // K quarter

    if (tid == 0) len_sh = Tlen;
    if (tid < 2 * 4 * CH) ((float*)hbuf)[tid] = 0.0f;  // h0 = 0 (both buffers)

    // W_hh quarter row -> registers (32 floats = 8 dwordx4 loads)
    float w[32];
    {
        const float4* wrow = (const float4*)(W_hh + i * Hdim + q * 32);
        #pragma unroll
        for (int k = 0; k < 8; k++) {
            float4 t4 = wrow[k];
            w[4 * k + 0] = t4.x; w[4 * k + 1] = t4.y;
            w[4 * k + 2] = t4.z; w[4 * k + 3] = t4.w;
        }
    }
    const float bias = b_ih[i] + b_hh[i];

    // Decode this block's one-hot rows: x[b] is 512 KB contiguous; float4
    // coalesced grid-stride over the block. Exactly one element/row is 1.
    const float4* xb = (const float4*)(x + (size_t)b * Tlen * Vocab);
    for (int k = tid; k < (Tlen * Vocab) / 4; k += NTHR) {
        float4 v = xb[k];
        int c = -1;
        if      (v.x > 0.5f) c = 0;
        else if (v.y > 0.5f) c = 1;
        else if (v.z > 0.5f) c = 2;
        else if (v.w > 0.5f) c = 3;
        if (c >= 0) syms[k >> 5] = ((k & 31) << 2) + c;  // 32 float4 per row
    }
    __syncthreads();

    // length = first t with sym==0 (pad), else Tlen
    {
        int lm = Tlen;
        for (int k = tid; k < Tlen; k += NTHR)
            if (syms[k] == 0 && k < lm) lm = k;
        if (lm < Tlen) atomicMin(&len_sh, lm);
    }
    __syncthreads();
    const int len = len_sh;

    // Pin W in VGPRs: empty asm makes the values non-rematerializable, so
    // the allocator cannot sink the global loads back into the loop.
    #pragma unroll
    for (int k = 0; k < 32; k += 4)
        asm volatile("" : "+v"(w[k]), "+v"(w[k + 1]), "+v"(w[k + 2]), "+v"(w[k + 3]));

    // pre pipeline: sym fetched at t+2, wt row at t+1
    float pre_v = 0.0f;
    int   sn1 = 0;
    if (len > 0) pre_v = wt[(syms[0] - 1) * Hdim + i];
    if (len > 1) sn1 = syms[1];

    const int rdoff = q * CH;
    for (int t = 0; t < len; t++) {
        float pre_n = 0.0f;
        if (t + 1 < len) pre_n = wt[(sn1 - 1) * Hdim + i];
        int sn2 = syms[(t + 2 < Tlen) ? (t + 2) : (Tlen - 1)];

        const float4* hsrc = (const float4*)(hbuf[t & 1] + rdoff);
        float ax = 0.0f, ay = 0.0f, az = 0.0f, aw = 0.0f;
        #pragma unroll
        for (int k = 0; k < 8; k++) {
            float4 hv = hsrc[k];
            ax = fmaf(w[4 * k + 0], hv.x, ax);
            ay = fmaf(w[4 * k + 1], hv.y, ay);
            az = fmaf(w[4 * k + 2], hv.z, az);
            aw = fmaf(w[4 * k + 3], hv.w, aw);
        }
        float sum = (ax + ay) + (az + aw);
        sum += __shfl_xor(sum, 1, 64);   // combine K quarters
        sum += __shfl_xor(sum, 2, 64);
        float hn = tanh_fast(sum + pre_v + bias);
        if (q == 0) hbuf[(t + 1) & 1][(i >> 5) * CH + (i & 31)] = hn;
        pre_v = pre_n;
        sn1 = sn2;
        __syncthreads();
    }

    // epilogue: hidden state + softmax head
    const float* hf = hbuf[len & 1];
    if (tid < Hdim)
        out[2 * Bsz + b * Hdim + tid] = hf[(tid >> 5) * CH + (tid & 31)];
    if (tid < 64) {
        float h0 = hf[(tid >> 5) * CH + (tid & 31)];
        int j = tid + 64;
        float h1 = hf[(j >> 5) * CH + (j & 31)];
        float p0 = W_out[tid] * h0 + W_out[64 + tid] * h1;
        float p1 = W_out[128 + tid] * h0 + W_out[192 + tid] * h1;
        #pragma unroll
        for (int off = 32; off > 0; off >>= 1) {
            p0 += __shfl_down(p0, off, 64);
            p1 += __shfl_down(p1, off, 64);
        }
        if (tid == 0) {
            float l0 = p0 + b_out[0], l1 = p1 + b_out[1];
            float m  = fmaxf(l0, l1);
            float e0 = __expf(l0 - m), e1 = __expf(l1 - m);
            float d  = e0 + e1;
            out[b * 2 + 0] = e0 / d;
            out[b * 2 + 1] = e1 / d;
        }
    }
}

extern "C" void kernel_launch(void* const* d_in, const int* in_sizes, int n_in,
                              void* d_out, int out_size, void* d_ws, size_t ws_size,
                              hipStream_t stream) {
    const float* x     = (const float*)d_in[0];
    const float* W_ih  = (const float*)d_in[1];
    const float* W_hh  = (const float*)d_in[2];
    const float* b_ih  = (const float*)d_in[3];
    const float* b_hh  = (const float*)d_in[4];
    const float* W_out = (const float*)d_in[5];
    const float* b_out = (const float*)d_in[6];
    float* out = (float*)d_out;

    float* wt = (float*)d_ws;  // (V-1) x H floats = 65 KB

    const int NTRN = (Hdim * (Vocab - 1) + 255) / 256;  // 64 blocks
    transpose_kernel<<<NTRN, 256, 0, stream>>>(W_ih, wt);
    rnn_kernel<<<Bsz, NTHR, 0, stream>>>(x, wt, W_hh, b_ih, b_hh, W_out, b_out, out);
}

// Round 3
// 535.325 us; speedup vs baseline: 1.3065x; 1.2588x over previous
//
#include <hip/hip_runtime.h>
#include <stdint.h>

#define Bsz   256
#define Tlen  1024
#define Vocab 128
#define Hdim  128
#define NTHR  512
#define CH    36   // padded LDS chunk stride in floats (32 data + 4 pad)
#define WTN   ((Vocab - 1) * Hdim)   // 127*128 = 16256 floats

__device__ __forceinline__ float tanh_fast(float x) {
    // tanh(x) = 1 - 2/(exp2(2x*log2e)+1); exact limits at +-inf
    float e = __builtin_amdgcn_exp2f(x * 2.885390081777927f);
    return 1.0f - 2.0f * __builtin_amdgcn_rcpf(e + 1.0f);
}

// quad-level butterfly adds via DPP (VALU-speed, no LDS pipe)
__device__ __forceinline__ float dpp_xor1(float s) {
    return __int_as_float(__builtin_amdgcn_mov_dpp(__float_as_int(s), 0xB1, 0xF, 0xF, true)); // quad_perm(1,0,3,2)
}
__device__ __forceinline__ float dpp_xor2(float s) {
    return __int_as_float(__builtin_amdgcn_mov_dpp(__float_as_int(s), 0x4E, 0xF, 0xF, true)); // quad_perm(2,3,0,1)
}

// Tiny prep: transpose W_ih (H x V-1) -> wt (V-1 x H), coalesced both sides enough.
__global__ __launch_bounds__(256) void transpose_kernel(
    const float* __restrict__ W_ih, float* __restrict__ wt)
{
    int idx = blockIdx.x * 256 + threadIdx.x;
    if (idx < WTN) {
        int h = idx / (Vocab - 1);
        int f = idx - h * (Vocab - 1);
        wt[f * Hdim + h] = W_ih[idx];   // wt[f][h] = W_ih[h][f]
    }
}

// One block (512 thr, 8 waves) per sequence. Lane quad owns h-element
// i = wave*16 + (l>>2); each lane does 32 of 128 MACs with its W_hh
// quarter-row pinned in VGPRs (in-loop asm pin). h double-buffered in LDS,
// quarter chunks at stride 36 floats (conflict-free b128). wt staged in LDS
// so the t-loop has ZERO global memory ops.
__global__ __launch_bounds__(NTHR, 2) void rnn_kernel(
    const float* __restrict__ x, const float* __restrict__ wt,
    const float* __restrict__ W_hh,
    const float* __restrict__ b_ih, const float* __restrict__ b_hh,
    const float* __restrict__ W_out, const float* __restrict__ b_out,
    float* __restrict__ out)
{
    __shared__ float wt_s[WTN];        // 65 KB
    __shared__ int   syms[Tlen];       // 4 KB
    __shared__ float hbuf[2][4 * CH];
    __shared__ int   len_sh;

    const int tid  = threadIdx.x;
    const int b    = blockIdx.x;
    const int wave = tid >> 6;
    const int l    = tid & 63;
    const int i    = (wave << 4) + (l >> 2);  // owned h element, 0..127
    const int q    = l & 3;                   // K quarter

    if (tid == 0) len_sh = Tlen;
    if (tid < 2 * 4 * CH) ((float*)hbuf)[tid] = 0.0f;  // h0 = 0 (both buffers)

    // W_hh quarter row -> registers (32 floats = 8 dwordx4 loads)
    float w[32];
    {
        const float4* wrow = (const float4*)(W_hh + i * Hdim + q * 32);
        #pragma unroll
        for (int k = 0; k < 8; k++) {
            float4 t4 = wrow[k];
            w[4 * k + 0] = t4.x; w[4 * k + 1] = t4.y;
            w[4 * k + 2] = t4.z; w[4 * k + 3] = t4.w;
        }
    }
    const float bias = b_ih[i] + b_hh[i];

    // stage wt -> LDS, coalesced float4
    {
        const float4* src = (const float4*)wt;
        float4* dst = (float4*)wt_s;
        for (int k = tid; k < WTN / 4; k += NTHR) dst[k] = src[k];
    }

    // Decode this block's one-hot rows (512 KB contiguous, float4 coalesced).
    const float4* xb = (const float4*)(x + (size_t)b * Tlen * Vocab);
    for (int k = tid; k < (Tlen * Vocab) / 4; k += NTHR) {
        float4 v = xb[k];
        int c = -1;
        if      (v.x > 0.5f) c = 0;
        else if (v.y > 0.5f) c = 1;
        else if (v.z > 0.5f) c = 2;
        else if (v.w > 0.5f) c = 3;
        if (c >= 0) syms[k >> 5] = ((k & 31) << 2) + c;  // 32 float4 per row
    }
    __syncthreads();

    // length = first t with sym==0 (pad), else Tlen
    {
        int lm = Tlen;
        for (int k = tid; k < Tlen; k += NTHR)
            if (syms[k] == 0 && k < lm) lm = k;
        if (lm < Tlen) atomicMin(&len_sh, lm);
    }
    __syncthreads();
    const int len = len_sh;

    // pre pipeline: row value for t ready (pre_v), t+1 in flight (p_t1),
    // symbol for t+2 in register (s_t2).
    float pre_v = 0.0f, p_t1 = 0.0f;
    int   s_t2 = 1;
    if (len > 0) pre_v = wt_s[(syms[0] - 1) * Hdim + i];
    if (len > 1) p_t1  = wt_s[(syms[1] - 1) * Hdim + i];
    if (len > 2) s_t2  = syms[2];

    const int rdoff = q * CH;
    const int wroff = (i >> 5) * CH + (i & 31);
    for (int t = 0; t < len; t++) {
        // Pin W in VGPRs EVERY iteration: "+v" makes the values opaque
        // redefinitions, so the allocator cannot re-load them from memory.
        #pragma unroll
        for (int k = 0; k < 32; k += 8)
            asm volatile("" : "+v"(w[k]), "+v"(w[k+1]), "+v"(w[k+2]), "+v"(w[k+3]),
                             "+v"(w[k+4]), "+v"(w[k+5]), "+v"(w[k+6]), "+v"(w[k+7]));

        float p_t2 = wt_s[(s_t2 - 1) * Hdim + i];         // LDS, for t+2
        int   s_t3 = (t + 3 < len) ? syms[t + 3] : 1;

        const float4* hsrc = (const float4*)(hbuf[t & 1] + rdoff);
        float ax = 0.0f, ay = 0.0f, az = 0.0f, aw = 0.0f;
        #pragma unroll
        for (int k = 0; k < 8; k++) {
            float4 hv = hsrc[k];
            ax = fmaf(w[4 * k + 0], hv.x, ax);
            ay = fmaf(w[4 * k + 1], hv.y, ay);
            az = fmaf(w[4 * k + 2], hv.z, az);
            aw = fmaf(w[4 * k + 3], hv.w, aw);
        }
        float sum = (ax + ay) + (az + aw);
        sum += dpp_xor1(sum);            // combine K quarters (VALU DPP)
        sum += dpp_xor2(sum);
        float hn = tanh_fast(sum + pre_v + bias);
        if (q == 0) hbuf[(t + 1) & 1][wroff] = hn;
        pre_v = p_t1; p_t1 = p_t2; s_t2 = s_t3;
        __syncthreads();
    }

    // epilogue: hidden state + softmax head
    const float* hf = hbuf[len & 1];
    if (tid < Hdim)
        out[2 * Bsz + b * Hdim + tid] = hf[(tid >> 5) * CH + (tid & 31)];
    if (tid < 64) {
        float h0 = hf[(tid >> 5) * CH + (tid & 31)];
        int j = tid + 64;
        float h1 = hf[(j >> 5) * CH + (j & 31)];
        float p0 = W_out[tid] * h0 + W_out[64 + tid] * h1;
        float p1 = W_out[128 + tid] * h0 + W_out[192 + tid] * h1;
        #pragma unroll
        for (int off = 32; off > 0; off >>= 1) {
            p0 += __shfl_down(p0, off, 64);
            p1 += __shfl_down(p1, off, 64);
        }
        if (tid == 0) {
            float l0 = p0 + b_out[0], l1 = p1 + b_out[1];
            float m  = fmaxf(l0, l1);
            float e0 = __expf(l0 - m), e1 = __expf(l1 - m);
            float d  = e0 + e1;
            out[b * 2 + 0] = e0 / d;
            out[b * 2 + 1] = e1 / d;
        }
    }
}

extern "C" void kernel_launch(void* const* d_in, const int* in_sizes, int n_in,
                              void* d_out, int out_size, void* d_ws, size_t ws_size,
                              hipStream_t stream) {
    const float* x     = (const float*)d_in[0];
    const float* W_ih  = (const float*)d_in[1];
    const float* W_hh  = (const float*)d_in[2];
    const float* b_ih  = (const float*)d_in[3];
    const float* b_hh  = (const float*)d_in[4];
    const float* W_out = (const float*)d_in[5];
    const float* b_out = (const float*)d_in[6];
    float* out = (float*)d_out;

    float* wt = (float*)d_ws;  // (V-1) x H floats = 65 KB

    const int NTRN = (WTN + 255) / 256;  // 64 blocks
    transpose_kernel<<<NTRN, 256, 0, stream>>>(W_ih, wt);
    rnn_kernel<<<Bsz, NTHR, 0, stream>>>(x, wt, W_hh, b_ih, b_hh, W_out, b_out, out);
}